// Round 6
// baseline (326.956 us; speedup 1.0000x reference)
//
#include <hip/hip_runtime.h>
#include <hip/hip_bf16.h>

#define D 64
#define K 400
#define KT 25            // K/16 code tiles
#define BLOCK 512
#define WPB (BLOCK / 64) // 8 waves per block

typedef _Float16 f16x8 __attribute__((ext_vector_type(8)));
typedef float f32x4 __attribute__((ext_vector_type(4)));

// ws layout: [whi: KT*2*64 f16x8 = 51200 B][wcn: 400 f32 = 1600 B][wlo: 51200 B]
// LDS stages the first 52800 B (hi frags + scaled norms); lo streams from L2.
#define WHI_BYTES (KT * 2 * 64 * 16)
#define WCN_BYTES (K * 4)
#define LDS_BYTES (WHI_BYTES + WCN_BYTES)   // 52800 -> 3 blocks/CU
#define WS_NEED (LDS_BYTES + WHI_BYTES)

// argmin_k ||e_k||^2 - 2 x.e_k via f16 hi/lo split (22-bit effective):
//   2e = eh + 2^-11 el,  x = xh + 2^-11 xl  (el, xl stored pre-scaled by 2^11)
//   m = [xh.eh] + 2^-11 [xh.el + xl.eh - 2048||e||^2]   (argmax m)
// -2048||e||^2 enters as the C-operand of the lo (cross) MFMA chain.
__global__ __launch_bounds__(128) void vq_prep(const float* __restrict__ emb,
                                               _Float16* __restrict__ whi,
                                               float* __restrict__ wcn,
                                               _Float16* __restrict__ wlo) {
  const int t = blockIdx.x;      // 25 blocks
  const int tid = threadIdx.x;   // 128: c = tid>>6, l = tid&63
  const int c = tid >> 6;
  const int l = tid & 63;
  const int code = t * 16 + (l & 15);
  const int kb = ((l >> 4) << 3) + c * 32;
  const float* ep = emb + code * D + kb;
  float v[8];
  *(float4*)&v[0] = *(const float4*)ep;
  *(float4*)&v[4] = *(const float4*)(ep + 4);
  _Float16 hi[8], lo[8];
#pragma unroll
  for (int j = 0; j < 8; ++j) {
    float s = 2.0f * v[j];
    _Float16 h = (_Float16)s;
    float r = s - (float)h;
    hi[j] = h;
    lo[j] = (_Float16)(r * 2048.0f); // pre-scaled: stays f16-normal
  }
  const int idx = ((t * 2 + c) * 64 + l) * 8;
  *(f16x8*)(whi + idx) = *(f16x8*)&hi[0];
  *(f16x8*)(wlo + idx) = *(f16x8*)&lo[0];
  if (tid < 16) {
    const float* np = emb + (t * 16 + tid) * D;
    float s = 0.f;
#pragma unroll
    for (int d = 0; d < D; ++d) s = fmaf(np[d], np[d], s);
    wcn[t * 16 + tid] = -2048.0f * s;
  }
}

__global__ __launch_bounds__(BLOCK, 6) void vq_main(
    const float* __restrict__ x,
    const float* __restrict__ ws,     // [whi][wcn][wlo]
    const float* __restrict__ emb,
    float* __restrict__ out,
    int nrows) {
  __shared__ __align__(16) unsigned char smem[LDS_BYTES];
  const _Float16* sHi = (const _Float16*)smem;
  const float* sCn = (const float*)(smem + WHI_BYTES);
  const f16x8* Blo = (const f16x8*)((const char*)ws + LDS_BYTES);

  const int tid = threadIdx.x;
  // ---- stage hi frags + scaled norms into LDS (contiguous copy) ----
  {
    const float4* src = (const float4*)ws;
    float4* dst = (float4*)smem;
    for (int i = tid; i < LDS_BYTES / 16; i += BLOCK) dst[i] = src[i];
  }
  __syncthreads();

  const int lane = tid & 63;
  const int wid = tid >> 6;
  const int gw = blockIdx.x * WPB + wid;
  const int row0 = gw << 5;          // 32 rows per wave
  if (row0 >= nrows) return;

  const int l15 = lane & 15;
  const int q = lane >> 4;

  // ---- load + split A fragments (2 row-tiles x 2 k-tiles) ----
  f16x8 xh[2][2], xl[2][2];
#pragma unroll
  for (int a = 0; a < 2; ++a)
#pragma unroll
    for (int c = 0; c < 2; ++c) {
      const float* xp = x + (size_t)(row0 + a * 16 + l15) * D + q * 8 + c * 32;
      float v[8];
      *(float4*)&v[0] = *(const float4*)xp;
      *(float4*)&v[4] = *(const float4*)(xp + 4);
      _Float16 hh[8], ll[8];
#pragma unroll
      for (int j = 0; j < 8; ++j) {
        _Float16 h = (_Float16)v[j];
        float r = v[j] - (float)h;
        hh[j] = h;
        ll[j] = (_Float16)(r * 2048.0f);
      }
      xh[a][c] = *(f16x8*)&hh[0];
      xl[a][c] = *(f16x8*)&ll[0];
    }

  float bestm[2][4];
  int bestt[2][4];
#pragma unroll
  for (int a = 0; a < 2; ++a)
#pragma unroll
    for (int i = 0; i < 4; ++i) {
      bestm[a][i] = -3.4e38f;
      bestt[a][i] = 0;
    }

  // ---- 25 code tiles, fully unrolled (imm-offset LDS reads) ----
#pragma unroll
  for (int t = 0; t < KT; ++t) {
    float cn = sCn[t * 16 + l15];
    f32x4 Cn = {cn, cn, cn, cn};
    const f32x4 Z = {0.f, 0.f, 0.f, 0.f};

    // k-columns sequenced to keep live B at 8 regs
    f16x8 bh = *(const f16x8*)&sHi[((t * 2 + 0) * 64 + lane) * 8];
    f16x8 bl = Blo[(t * 2 + 0) * 64 + lane];
    f32x4 ah0 = __builtin_amdgcn_mfma_f32_16x16x32_f16(xh[0][0], bh, Z, 0, 0, 0);
    f32x4 ah1 = __builtin_amdgcn_mfma_f32_16x16x32_f16(xh[1][0], bh, Z, 0, 0, 0);
    f32x4 al0 = __builtin_amdgcn_mfma_f32_16x16x32_f16(xh[0][0], bl, Cn, 0, 0, 0);
    f32x4 al1 = __builtin_amdgcn_mfma_f32_16x16x32_f16(xh[1][0], bl, Cn, 0, 0, 0);
    al0 = __builtin_amdgcn_mfma_f32_16x16x32_f16(xl[0][0], bh, al0, 0, 0, 0);
    al1 = __builtin_amdgcn_mfma_f32_16x16x32_f16(xl[1][0], bh, al1, 0, 0, 0);

    bh = *(const f16x8*)&sHi[((t * 2 + 1) * 64 + lane) * 8];
    bl = Blo[(t * 2 + 1) * 64 + lane];
    ah0 = __builtin_amdgcn_mfma_f32_16x16x32_f16(xh[0][1], bh, ah0, 0, 0, 0);
    ah1 = __builtin_amdgcn_mfma_f32_16x16x32_f16(xh[1][1], bh, ah1, 0, 0, 0);
    al0 = __builtin_amdgcn_mfma_f32_16x16x32_f16(xh[0][1], bl, al0, 0, 0, 0);
    al1 = __builtin_amdgcn_mfma_f32_16x16x32_f16(xh[1][1], bl, al1, 0, 0, 0);
    al0 = __builtin_amdgcn_mfma_f32_16x16x32_f16(xl[0][1], bh, al0, 0, 0, 0);
    al1 = __builtin_amdgcn_mfma_f32_16x16x32_f16(xl[1][1], bh, al1, 0, 0, 0);

#pragma unroll
    for (int i = 0; i < 4; ++i) {
      float m0 = fmaf(al0[i], 4.8828125e-4f, ah0[i]);
      bool g0 = m0 > bestm[0][i];
      bestm[0][i] = g0 ? m0 : bestm[0][i];
      bestt[0][i] = g0 ? t : bestt[0][i];
      float m1 = fmaf(al1[i], 4.8828125e-4f, ah1[i]);
      bool g1 = m1 > bestm[1][i];
      bestm[1][i] = g1 ? m1 : bestm[1][i];
      bestt[1][i] = g1 ? t : bestt[1][i];
    }
  }

  // ---- argmin reduce across the 16 lanes of each row-group + write ----
#pragma unroll
  for (int a = 0; a < 2; ++a) {
    float bv[4];
    int bk[4];
#pragma unroll
    for (int i = 0; i < 4; ++i) {
      bv[i] = bestm[a][i];
      bk[i] = bestt[a][i] * 16 + l15;
    }
#pragma unroll
    for (int m = 1; m <= 8; m <<= 1) {
#pragma unroll
      for (int i = 0; i < 4; ++i) {
        float ov = __shfl_xor(bv[i], m, 64);
        int ok = __shfl_xor(bk[i], m, 64);
        bool take = (ov > bv[i]) || ((ov == bv[i]) && (ok < bk[i]));
        bv[i] = take ? ov : bv[i];
        bk[i] = take ? ok : bk[i];
      }
    }
    // lane writes 64B of row (lane>>2); its group (lane>>4) holds that row
    int j = (lane >> 2) & 3;
    int k01 = (j & 1) ? bk[1] : bk[0];
    int k23 = (j & 1) ? bk[3] : bk[2];
    int kk = (j & 2) ? k23 : k01;
    int r = row0 + a * 16 + (lane >> 2);
    const float4* src = (const float4*)(emb + kk * D + (lane & 3) * 16);
    float4* dst = (float4*)(out + (size_t)r * D + (lane & 3) * 16);
#pragma unroll
    for (int s = 0; s < 4; ++s) dst[s] = src[s];
  }
}

// ---- fallback (ws too small): known-correct scalar kernel ----
__global__ __launch_bounds__(256) void vq_naive(const float* __restrict__ x,
                                                const float* __restrict__ emb,
                                                float* __restrict__ out,
                                                int nrows) {
  __shared__ float s_norm[K];
  for (int k = threadIdx.x; k < K; k += blockDim.x) {
    const float* e = emb + k * D;
    float s = 0.f;
#pragma unroll
    for (int d = 0; d < D; ++d) s = fmaf(e[d], e[d], s);
    s_norm[k] = s;
  }
  __syncthreads();
  int r = blockIdx.x * blockDim.x + threadIdx.x;
  if (r >= nrows) return;
  float xr[D];
  const float4* xv = (const float4*)(x + (size_t)r * D);
#pragma unroll
  for (int j = 0; j < D / 4; ++j) {
    float4 t = xv[j];
    xr[4 * j] = t.x; xr[4 * j + 1] = t.y; xr[4 * j + 2] = t.z; xr[4 * j + 3] = t.w;
  }
  float best = 3.4e38f;
  int bestk = 0;
#pragma unroll 2
  for (int k = 0; k < K; ++k) {
    const float* e = emb + k * D;
    float acc = 0.f;
#pragma unroll
    for (int d = 0; d < D; ++d) acc = fmaf(e[d], xr[d], acc);
    float score = fmaf(-2.f, acc, s_norm[k]);
    if (score < best) { best = score; bestk = k; }
  }
  float4* ov = (float4*)(out + (size_t)r * D);
  const float4* ev = (const float4*)(emb + (size_t)bestk * D);
#pragma unroll
  for (int j = 0; j < D / 4; ++j) ov[j] = ev[j];
}

extern "C" void kernel_launch(void* const* d_in, const int* in_sizes, int n_in,
                              void* d_out, int out_size, void* d_ws, size_t ws_size,
                              hipStream_t stream) {
  const float* x = (const float*)d_in[0];
  const float* emb = (const float*)d_in[1];
  float* out = (float*)d_out;
  int nrows = in_sizes[0] / D; // 262144

  if (ws_size < (size_t)WS_NEED) {
    vq_naive<<<(nrows + 255) / 256, 256, 0, stream>>>(x, emb, out, nrows);
    return;
  }

  _Float16* whi = (_Float16*)d_ws;
  float* wcn = (float*)((char*)d_ws + WHI_BYTES);
  _Float16* wlo = (_Float16*)((char*)d_ws + LDS_BYTES);

  vq_prep<<<KT, 128, 0, stream>>>(emb, whi, wcn, wlo);
  int ngrp = (nrows + 31) / 32;         // 32 rows per wave
  int nblk = (ngrp + WPB - 1) / WPB;    // 8 waves per block -> 1024 blocks
  vq_main<<<nblk, BLOCK, 0, stream>>>(x, (const float*)d_ws, emb, out, nrows);
}